// Round 10
// baseline (529.863 us; speedup 1.0000x reference)
//
#include <hip/hip_runtime.h>

#define D 512
#define D4 (D / 4)
#define MAXC 256
#define FEPS 1e-12f
#define FBIG 3.0e38f
#define DROWS 8
#define PGRP 8     // i-rows per k_pos block
#define PTHR 128   // k_pos threads (j-stream lanes)
#define PGRIDX 32  // i-groups (covers class counts up to 256)

__device__ __forceinline__ float wave_rsum(float v) {
#pragma unroll
    for (int o = 32; o > 0; o >>= 1) v += __shfl_down(v, o);
    return v;
}

__device__ __forceinline__ float wave_rsum_all(float v) {
#pragma unroll
    for (int o = 32; o > 0; o >>= 1) v += __shfl_xor(v, o);
    return v;
}

__device__ __forceinline__ float dot4(const float4 a, const float4 b) {
    return a.x * b.x + a.y * b.y + a.z * b.z + a.w * b.w;
}

// top_k tie-break: higher value wins; equal values -> smaller global index wins
__device__ __forceinline__ bool better(float v1, int j1, float v2, int j2) {
    return (v1 > v2) || (v1 == v2 && (unsigned)j1 < (unsigned)j2);
}

__device__ __forceinline__ void ins3(float v, int j, float& t0, float& t1, float& t2,
                                     int& x0, int& x1, int& x2) {
    if (j < 0) return;
    if (better(v, j, t0, x0)) { t2 = t1; x2 = x1; t1 = t0; x1 = x0; t0 = v; x0 = j; }
    else if (better(v, j, t1, x1)) { t2 = t1; x2 = x1; t1 = v; x1 = j; }
    else if (better(v, j, t2, x2)) { t2 = v; x2 = j; }
}

// --- 1. row L2-normalize + a2[i] + fused class histogram ---
__global__ void k_normalize(const float* __restrict__ emb, const int* __restrict__ targets,
                            float* __restrict__ embn, float* __restrict__ a2,
                            int* __restrict__ ccount) {
    const int i = blockIdx.x;
    const int tid = threadIdx.x;  // 128 threads, float4 each
    __shared__ float red[2];
    const float4 x = ((const float4*)(emb + (size_t)i * D))[tid];
    float ss = x.x * x.x + x.y * x.y + x.z * x.z + x.w * x.w;
    ss = wave_rsum(ss);
    if ((tid & 63) == 0) red[tid >> 6] = ss;
    __syncthreads();
    const float tot = red[0] + red[1];
    const float inv = 1.0f / fmaxf(sqrtf(tot), FEPS);
    const float4 y = make_float4(x.x * inv, x.y * inv, x.z * inv, x.w * inv);
    ((float4*)(embn + (size_t)i * D))[tid] = y;
    float s2 = y.x * y.x + y.y * y.y + y.z * y.z + y.w * y.w;
    s2 = wave_rsum(s2);
    __syncthreads();
    if ((tid & 63) == 0) red[tid >> 6] = s2;
    __syncthreads();
    if (tid == 0) {
        a2[i] = red[0] + red[1];
        atomicAdd(&ccount[targets[i]], 1);
    }
}

// --- 2. per-class offset (in-block prefix reduce) + deterministic row lists ---
__global__ void k_build(const int* __restrict__ t, const int* __restrict__ ccount,
                        int* __restrict__ coff, int* __restrict__ clist, int n,
                        const int* __restrict__ ncls) {
    const int C = *ncls;
    const int c = blockIdx.x;  // grid = MAXC
    if (c >= C) return;
    __shared__ int pref[256];
    pref[threadIdx.x] = ((int)threadIdx.x < c) ? ccount[threadIdx.x] : 0;
    __syncthreads();
    for (int s = 128; s > 0; s >>= 1) {
        if (threadIdx.x < s) pref[threadIdx.x] += pref[threadIdx.x + s];
        __syncthreads();
    }
    int base = pref[0];
    if (threadIdx.x == 0) coff[c] = base;
    __shared__ int wtot[4];
    for (int start = 0; start < n; start += 256) {
        const int j = start + (int)threadIdx.x;
        const bool flag = (j < n) && (t[j] == c);
        const unsigned long long m = __ballot(flag);
        const int lane = threadIdx.x & 63;
        const int w = threadIdx.x >> 6;
        const int pre = __popcll(m & ((1ull << lane) - 1ull));
        if (lane == 0) wtot[w] = __popcll(m);
        __syncthreads();
        int woff = 0;
        for (int k = 0; k < w; ++k) woff += wtot[k];
        const int tot = wtot[0] + wtot[1] + wtot[2] + wtot[3];
        if (flag) clist[base + woff + pre] = j;
        base += tot;
        __syncthreads();
    }
}

// --- 3. class centers: grid (4 d-chunks x MAXC), 128 threads ---
__global__ void k_centers(const float* __restrict__ embn, const int* __restrict__ clist,
                          const int* __restrict__ coff, const int* __restrict__ ccount,
                          float* __restrict__ centers) {
    const int c = blockIdx.y;
    const int dchunk = blockIdx.x;      // 32 float4 slots each
    const int cnt = ccount[c];
    const int off = (cnt > 0) ? coff[c] : 0;
    const int tid = threadIdx.x;        // 128
    const int slot = tid & 31;
    const int rg = tid >> 5;            // 0..3
    float4 s = make_float4(0.f, 0.f, 0.f, 0.f);
    for (int mi = rg; mi < cnt; mi += 4) {
        const int j = clist[off + mi];
        const float4 e = ((const float4*)(embn + (size_t)j * D))[dchunk * 32 + slot];
        s.x += e.x; s.y += e.y; s.z += e.z; s.w += e.w;
    }
    __shared__ float4 part[4][32];
    part[rg][slot] = s;
    __syncthreads();
    if (rg == 0) {
        const float4 p0 = part[0][slot], p1 = part[1][slot], p2 = part[2][slot], p3 = part[3][slot];
        const float inv = 1.0f / fmaxf((float)cnt, 1e-6f);
        const float4 v = make_float4((p0.x + p1.x + p2.x + p3.x) * inv,
                                     (p0.y + p1.y + p2.y + p3.y) * inv,
                                     (p0.z + p1.z + p2.z + p3.z) * inv,
                                     (p0.w + p1.w + p2.w + p3.w) * inv);
        ((float4*)(centers + (size_t)c * D))[dchunk * 32 + slot] = v;
    }
}

// --- 4. d_neg_min: 8 rows per block, one thread per class (cc2 inline) ---
__global__ void k_dneg(const float* __restrict__ embn, const float* __restrict__ a2,
                       const int* __restrict__ t, const float* __restrict__ centers,
                       float* __restrict__ dneg, int n, const int* __restrict__ ncls) {
    const int C = *ncls;
    const int i0 = blockIdx.x * DROWS;
    __shared__ __align__(16) float lrow[DROWS][D];
    __shared__ float la2[DROWS];
    __shared__ int lt[DROWS];
    __shared__ float mins[DROWS][128];
#pragma unroll
    for (int r = 0; r < DROWS; ++r) {
        if (i0 + r < n)
            ((float4*)lrow[r])[threadIdx.x] =
                ((const float4*)(embn + (size_t)(i0 + r) * D))[threadIdx.x];
    }
    if (threadIdx.x < DROWS) {
        const int ii = i0 + (int)threadIdx.x;
        la2[threadIdx.x] = (ii < n) ? a2[ii] : 0.f;
        lt[threadIdx.x] = (ii < n) ? t[ii] : -1;
    }
    __syncthreads();
    const int c = threadIdx.x;
    float best[DROWS];
    if (c < C) {
        float acc[DROWS];
#pragma unroll
        for (int r = 0; r < DROWS; ++r) acc[r] = 0.f;
        float c2acc = 0.f;
        const float4* cp = (const float4*)(centers + (size_t)c * D);
        for (int k = 0; k < D4; ++k) {
            const float4 cv = cp[k];
            c2acc += dot4(cv, cv);
#pragma unroll
            for (int r = 0; r < DROWS; ++r) {
                const float4 ev = ((const float4*)lrow[r])[k];
                acc[r] += cv.x * ev.x + cv.y * ev.y + cv.z * ev.z + cv.w * ev.w;
            }
        }
#pragma unroll
        for (int r = 0; r < DROWS; ++r) {
            const float sq = la2[r] + c2acc - 2.f * acc[r];
            float dv = sqrtf(fmaxf(sq, FEPS));
            if (lt[r] == c) dv = FBIG;
            best[r] = dv;
        }
    } else {
#pragma unroll
        for (int r = 0; r < DROWS; ++r) best[r] = FBIG;
    }
#pragma unroll
    for (int r = 0; r < DROWS; ++r) mins[r][threadIdx.x] = best[r];
    __syncthreads();
    for (int s = 64; s > 0; s >>= 1) {
        if (threadIdx.x < s) {
#pragma unroll
            for (int r = 0; r < DROWS; ++r)
                mins[r][threadIdx.x] = fminf(mins[r][threadIdx.x], mins[r][threadIdx.x + s]);
        }
        __syncthreads();
    }
    if (threadIdx.x < DROWS && i0 + (int)threadIdx.x < n)
        dneg[i0 + threadIdx.x] = mins[threadIdx.x][0];
}

// --- 5. fused positives: k_dneg-style row streams + top3 + d_pos + loss ---
// Block = 8 same-class rows staged in LDS (one-time). Thread = one class-member
// j-row streamed from GLOBAL through registers (k_dneg's proven pattern): no
// per-chunk LDS staging, no vmcnt choke, loads pipeline freely.
__global__ __launch_bounds__(PTHR) void k_pos(
    const float* __restrict__ embn, const float* __restrict__ a2,
    const int* __restrict__ clist, const int* __restrict__ coff,
    const int* __restrict__ ccount, const float* __restrict__ dneg,
    float* __restrict__ accum, int* __restrict__ done,
    float* __restrict__ out, int nblocks) {
    const int c = blockIdx.y;
    const int m = ccount[c];
    const int r0 = blockIdx.x * PGRP;  // class-list row offset of this block
    const int tid = threadIdx.x;
    const int lane = tid & 63, wav = tid >> 6;

    __shared__ __align__(16) float lrow[PGRP][D];  // 16 KB
    __shared__ float la2[PGRP];
    __shared__ int gi_s[PGRP];
    __shared__ float cv_s[PGRP][PTHR + 1];         // padded: owner scan conflict-free
    __shared__ int cj_s[PGRP][PTHR + 1];
    __shared__ int win_s[PGRP][3];
    __shared__ float blk_l[2], blk_v[2];

    float lsum = 0.f, vsum = 0.f;

    if (m > 0 && r0 < m) {  // block-uniform
        const int off = coff[c];
        const int nr = min(PGRP, m - r0);
        if (tid < PGRP) {
            const int gi = (tid < nr) ? clist[off + r0 + tid] : -1;
            gi_s[tid] = gi;
            la2[tid] = (gi >= 0) ? a2[gi] : 0.f;
        }
        for (int r = 0; r < nr; ++r) {
            const int gi = clist[off + r0 + r];
            ((float4*)lrow[r])[tid] = ((const float4*)(embn + (size_t)gi * D))[tid];
        }
        __syncthreads();

        // owner threads (tid < nr) keep running top3 across passes
        float tv0 = -FBIG, tv1 = -FBIG, tv2 = -FBIG;
        int tj0 = -1, tj1 = -1, tj2 = -1;

        for (int base = 0; base < m; base += PTHR) {
            const int j = base + tid;
            float acc[PGRP];
#pragma unroll
            for (int r = 0; r < PGRP; ++r) acc[r] = 0.f;
            int gj = -1;
            float a2j = 0.f;
            if (j < m) {
                gj = clist[off + j];
                a2j = a2[gj];
                const float4* gB = (const float4*)(embn + (size_t)gj * D);
                for (int k4 = 0; k4 < D4; k4 += 4) {
                    const float4 b0 = gB[k4], b1 = gB[k4 + 1];
                    const float4 b2 = gB[k4 + 2], b3 = gB[k4 + 3];
#pragma unroll
                    for (int r = 0; r < PGRP; ++r) {
                        const float4* lr = (const float4*)lrow[r];
                        acc[r] += dot4(lr[k4], b0);
                        acc[r] += dot4(lr[k4 + 1], b1);
                        acc[r] += dot4(lr[k4 + 2], b2);
                        acc[r] += dot4(lr[k4 + 3], b3);
                    }
                }
            }
            // emit candidates (sentinel for inactive/self)
#pragma unroll
            for (int r = 0; r < PGRP; ++r) {
                float v = -FBIG; int jj = -1;
                if (j < m && gj != gi_s[r]) {
                    v = la2[r] + a2j - 2.f * acc[r];
                    jj = gj;
                }
                cv_s[r][tid] = v;
                cj_s[r][tid] = jj;
            }
            __syncthreads();
            if (tid < nr) {  // ascending-j scan preserves top_k tie-break
                for (int q = 0; q < PTHR; ++q)
                    ins3(cv_s[tid][q], cj_s[tid][q], tv0, tv1, tv2, tj0, tj1, tj2);
            }
            __syncthreads();
        }

        if (tid < nr) { win_s[tid][0] = tj0; win_s[tid][1] = tj1; win_s[tid][2] = tj2; }
        __syncthreads();

        // d_pos + softplus per row; 2 waves round-robin the nr rows
        for (int r = wav; r < nr; r += 2) {
            const int j0 = win_s[r][0], j1 = win_s[r][1], j2 = win_s[r][2];
            if (j0 >= 0) {
                const int jA = j0;
                const int jB = (j1 >= 0) ? j1 : jA;
                const int jC = (j2 >= 0) ? j2 : jB;
                const float4* pi = (const float4*)lrow[r];
                const float4* p0 = (const float4*)(embn + (size_t)jA * D);
                const float4* p1 = (const float4*)(embn + (size_t)jB * D);
                const float4* p2 = (const float4*)(embn + (size_t)jC * D);
                float accp = 0.f;
#pragma unroll
                for (int s = 0; s < 2; ++s) {
                    const int k4 = lane + 64 * s;
                    const float4 a = pi[k4];
                    const float4 v0 = p0[k4], v1 = p1[k4], v2 = p2[k4];
                    const float cx = (v0.x + v1.x + v2.x) * (1.f / 3.f);
                    const float cy = (v0.y + v1.y + v2.y) * (1.f / 3.f);
                    const float cz = (v0.z + v1.z + v2.z) * (1.f / 3.f);
                    const float cw = (v0.w + v1.w + v2.w) * (1.f / 3.f);
                    const float dx = a.x - cx, dy = a.y - cy, dz = a.z - cz, dw = a.w - cw;
                    accp += dx * dx + dy * dy + dz * dz + dw * dw;
                }
                accp = wave_rsum_all(accp);
                const float dp = sqrtf(fmaxf(accp, FEPS));
                const float x = dp - dneg[gi_s[r]];
                lsum += fmaxf(x, 0.f) + log1pf(expf(-fabsf(x)));
                vsum += 1.f;
            }
        }
        if (lane == 0) { blk_l[wav] = lsum; blk_v[wav] = vsum; }
        __syncthreads();
        if (tid == 0) {
            atomicAdd(&accum[0], blk_l[0] + blk_l[1]);
            atomicAdd(&accum[1], blk_v[0] + blk_v[1]);
        }
    }

    // every block (including empty ones) signals completion; last one finalizes
    if (tid == 0) {
        __threadfence();
        const int prev = atomicAdd(done, 1);
        if (prev == nblocks - 1) {
            __threadfence();
            const float sl = atomicAdd(&accum[0], 0.0f);  // coherent-point read
            const float sv = atomicAdd(&accum[1], 0.0f);
            out[0] = sl / fmaxf(sv, 1.0f);
        }
    }
}

extern "C" void kernel_launch(void* const* d_in, const int* in_sizes, int n_in,
                              void* d_out, int out_size, void* d_ws, size_t ws_size,
                              hipStream_t stream) {
    const float* emb = (const float*)d_in[0];
    const int* targets = (const int*)d_in[1];
    const int* ncls = (const int*)d_in[2];
    const int n = in_sizes[1];  // 8192

    float* fp = (float*)d_ws;
    float* embn = fp;    fp += (size_t)n * D;
    float* a2 = fp;      fp += n;
    float* centers = fp; fp += (size_t)MAXC * D;
    float* dneg = fp;    fp += n;
    int* ccount = (int*)fp; fp += MAXC;
    float* accum = fp;   fp += 2;          // contiguous with ccount: one memset
    int* done = (int*)fp; fp += 1;
    int* coff = (int*)fp;   fp += MAXC;
    int* clist = (int*)fp;  fp += n;

    hipMemsetAsync(ccount, 0, (MAXC + 3) * sizeof(int), stream);

    const int npos = PGRIDX * MAXC;
    k_normalize<<<n, 128, 0, stream>>>(emb, targets, embn, a2, ccount);
    k_build<<<MAXC, 256, 0, stream>>>(targets, ccount, coff, clist, n, ncls);
    k_centers<<<dim3(4, MAXC), 128, 0, stream>>>(embn, clist, coff, ccount, centers);
    k_dneg<<<(n + DROWS - 1) / DROWS, 128, 0, stream>>>(embn, a2, targets, centers, dneg, n, ncls);
    k_pos<<<dim3(PGRIDX, MAXC), PTHR, 0, stream>>>(embn, a2, clist, coff, ccount, dneg,
                                                   accum, done, (float*)d_out, npos);
}

// Round 11
// 485.098 us; speedup vs baseline: 1.0923x; 1.0923x over previous
//
#include <hip/hip_runtime.h>

#define D 512
#define D4 (D / 4)
#define MAXC 256
#define FEPS 1e-12f
#define FBIG 3.0e38f
#define DROWS 8
#define NIG 32   // i-groups of 8 rows (covers class counts up to 256)
#define NJT 2    // j-halves (covers class counts up to 256)

__device__ __forceinline__ float wave_rsum(float v) {
#pragma unroll
    for (int o = 32; o > 0; o >>= 1) v += __shfl_down(v, o);
    return v;
}

__device__ __forceinline__ float wave_rsum_all(float v) {
#pragma unroll
    for (int o = 32; o > 0; o >>= 1) v += __shfl_xor(v, o);
    return v;
}

__device__ __forceinline__ float dot4(const float4 a, const float4 b) {
    return a.x * b.x + a.y * b.y + a.z * b.z + a.w * b.w;
}

// top_k tie-break: higher value wins; equal values -> smaller global index wins
__device__ __forceinline__ bool better(float v1, int j1, float v2, int j2) {
    return (v1 > v2) || (v1 == v2 && (unsigned)j1 < (unsigned)j2);
}

__device__ __forceinline__ void ins3(float v, int j, float& t0, float& t1, float& t2,
                                     int& x0, int& x1, int& x2) {
    if (j < 0) return;
    if (better(v, j, t0, x0)) { t2 = t1; x2 = x1; t1 = t0; x1 = x0; t0 = v; x0 = j; }
    else if (better(v, j, t1, x1)) { t2 = t1; x2 = x1; t1 = v; x1 = j; }
    else if (better(v, j, t2, x2)) { t2 = v; x2 = j; }
}

// --- 1. row L2-normalize + a2[i] + fused class histogram ---
__global__ void k_normalize(const float* __restrict__ emb, const int* __restrict__ targets,
                            float* __restrict__ embn, float* __restrict__ a2,
                            int* __restrict__ ccount) {
    const int i = blockIdx.x;
    const int tid = threadIdx.x;  // 128 threads, float4 each
    __shared__ float red[2];
    const float4 x = ((const float4*)(emb + (size_t)i * D))[tid];
    float ss = x.x * x.x + x.y * x.y + x.z * x.z + x.w * x.w;
    ss = wave_rsum(ss);
    if ((tid & 63) == 0) red[tid >> 6] = ss;
    __syncthreads();
    const float tot = red[0] + red[1];
    const float inv = 1.0f / fmaxf(sqrtf(tot), FEPS);
    const float4 y = make_float4(x.x * inv, x.y * inv, x.z * inv, x.w * inv);
    ((float4*)(embn + (size_t)i * D))[tid] = y;
    float s2 = y.x * y.x + y.y * y.y + y.z * y.z + y.w * y.w;
    s2 = wave_rsum(s2);
    __syncthreads();
    if ((tid & 63) == 0) red[tid >> 6] = s2;
    __syncthreads();
    if (tid == 0) {
        a2[i] = red[0] + red[1];
        atomicAdd(&ccount[targets[i]], 1);
    }
}

// --- 2. per-class offset (in-block prefix reduce) + deterministic row lists ---
__global__ void k_build(const int* __restrict__ t, const int* __restrict__ ccount,
                        int* __restrict__ coff, int* __restrict__ clist, int n,
                        const int* __restrict__ ncls) {
    const int C = *ncls;
    const int c = blockIdx.x;  // grid = MAXC
    if (c >= C) return;
    __shared__ int pref[256];
    pref[threadIdx.x] = ((int)threadIdx.x < c) ? ccount[threadIdx.x] : 0;
    __syncthreads();
    for (int s = 128; s > 0; s >>= 1) {
        if (threadIdx.x < s) pref[threadIdx.x] += pref[threadIdx.x + s];
        __syncthreads();
    }
    int base = pref[0];
    if (threadIdx.x == 0) coff[c] = base;
    __shared__ int wtot[4];
    for (int start = 0; start < n; start += 256) {
        const int j = start + (int)threadIdx.x;
        const bool flag = (j < n) && (t[j] == c);
        const unsigned long long m = __ballot(flag);
        const int lane = threadIdx.x & 63;
        const int w = threadIdx.x >> 6;
        const int pre = __popcll(m & ((1ull << lane) - 1ull));
        if (lane == 0) wtot[w] = __popcll(m);
        __syncthreads();
        int woff = 0;
        for (int k = 0; k < w; ++k) woff += wtot[k];
        const int tot = wtot[0] + wtot[1] + wtot[2] + wtot[3];
        if (flag) clist[base + woff + pre] = j;
        base += tot;
        __syncthreads();
    }
}

// --- 2b. K-major class-packed panel: panelT[k][col] = embn[clist[col]][k] ---
// Also packs a2 into class order. Coalesced reads AND writes via padded LDS tile.
__global__ __launch_bounds__(256) void k_transpose(
    const float* __restrict__ embn, const float* __restrict__ a2,
    const int* __restrict__ clist, float* __restrict__ panelT,
    float* __restrict__ a2p, int n) {
    const int col0 = blockIdx.x * 64;
    const int tid = threadIdx.x;  // 256
    const int lane = tid & 63;
    const int wav = tid >> 6;     // 0..3
    __shared__ float tile[64][65];
    __shared__ int gi_s[64];
    if (tid < 64) {
        const int gi = clist[col0 + tid];
        gi_s[tid] = gi;
        a2p[col0 + tid] = a2[gi];
    }
    __syncthreads();
    for (int kt = 0; kt < 8; ++kt) {
        const int k0 = kt * 64;
        if (kt) __syncthreads();  // previous tile fully read
#pragma unroll
        for (int p = 0; p < 16; ++p) {
            const int row = wav + p * 4;
            tile[row][lane] = embn[(size_t)gi_s[row] * D + k0 + lane];  // coalesced
        }
        __syncthreads();
#pragma unroll
        for (int p = 0; p < 16; ++p) {
            const int kk = wav + p * 4;
            panelT[(size_t)(k0 + kk) * n + col0 + lane] = tile[lane][kk];  // coalesced
        }
    }
}

// --- 3. class centers: grid (4 d-chunks x MAXC), 128 threads ---
__global__ void k_centers(const float* __restrict__ embn, const int* __restrict__ clist,
                          const int* __restrict__ coff, const int* __restrict__ ccount,
                          float* __restrict__ centers) {
    const int c = blockIdx.y;
    const int dchunk = blockIdx.x;      // 32 float4 slots each
    const int cnt = ccount[c];
    const int off = (cnt > 0) ? coff[c] : 0;
    const int tid = threadIdx.x;        // 128
    const int slot = tid & 31;
    const int rg = tid >> 5;            // 0..3
    float4 s = make_float4(0.f, 0.f, 0.f, 0.f);
    for (int mi = rg; mi < cnt; mi += 4) {
        const int j = clist[off + mi];
        const float4 e = ((const float4*)(embn + (size_t)j * D))[dchunk * 32 + slot];
        s.x += e.x; s.y += e.y; s.z += e.z; s.w += e.w;
    }
    __shared__ float4 part[4][32];
    part[rg][slot] = s;
    __syncthreads();
    if (rg == 0) {
        const float4 p0 = part[0][slot], p1 = part[1][slot], p2 = part[2][slot], p3 = part[3][slot];
        const float inv = 1.0f / fmaxf((float)cnt, 1e-6f);
        const float4 v = make_float4((p0.x + p1.x + p2.x + p3.x) * inv,
                                     (p0.y + p1.y + p2.y + p3.y) * inv,
                                     (p0.z + p1.z + p2.z + p3.z) * inv,
                                     (p0.w + p1.w + p2.w + p3.w) * inv);
        ((float4*)(centers + (size_t)c * D))[dchunk * 32 + slot] = v;
    }
}

// --- 4. d_neg_min: 8 rows per block, one thread per class (cc2 inline) ---
__global__ void k_dneg(const float* __restrict__ embn, const float* __restrict__ a2,
                       const int* __restrict__ t, const float* __restrict__ centers,
                       float* __restrict__ dneg, int n, const int* __restrict__ ncls) {
    const int C = *ncls;
    const int i0 = blockIdx.x * DROWS;
    __shared__ __align__(16) float lrow[DROWS][D];
    __shared__ float la2[DROWS];
    __shared__ int lt[DROWS];
    __shared__ float mins[DROWS][128];
#pragma unroll
    for (int r = 0; r < DROWS; ++r) {
        if (i0 + r < n)
            ((float4*)lrow[r])[threadIdx.x] =
                ((const float4*)(embn + (size_t)(i0 + r) * D))[threadIdx.x];
    }
    if (threadIdx.x < DROWS) {
        const int ii = i0 + (int)threadIdx.x;
        la2[threadIdx.x] = (ii < n) ? a2[ii] : 0.f;
        lt[threadIdx.x] = (ii < n) ? t[ii] : -1;
    }
    __syncthreads();
    const int c = threadIdx.x;
    float best[DROWS];
    if (c < C) {
        float acc[DROWS];
#pragma unroll
        for (int r = 0; r < DROWS; ++r) acc[r] = 0.f;
        float c2acc = 0.f;
        const float4* cp = (const float4*)(centers + (size_t)c * D);
        for (int k = 0; k < D4; ++k) {
            const float4 cv = cp[k];
            c2acc += dot4(cv, cv);
#pragma unroll
            for (int r = 0; r < DROWS; ++r) {
                const float4 ev = ((const float4*)lrow[r])[k];
                acc[r] += cv.x * ev.x + cv.y * ev.y + cv.z * ev.z + cv.w * ev.w;
            }
        }
#pragma unroll
        for (int r = 0; r < DROWS; ++r) {
            const float sq = la2[r] + c2acc - 2.f * acc[r];
            float dv = sqrtf(fmaxf(sq, FEPS));
            if (lt[r] == c) dv = FBIG;
            best[r] = dv;
        }
    } else {
#pragma unroll
        for (int r = 0; r < DROWS; ++r) best[r] = FBIG;
    }
#pragma unroll
    for (int r = 0; r < DROWS; ++r) mins[r][threadIdx.x] = best[r];
    __syncthreads();
    for (int s = 64; s > 0; s >>= 1) {
        if (threadIdx.x < s) {
#pragma unroll
            for (int r = 0; r < DROWS; ++r)
                mins[r][threadIdx.x] = fminf(mins[r][threadIdx.x], mins[r][threadIdx.x + s]);
        }
        __syncthreads();
    }
    if (threadIdx.x < DROWS && i0 + (int)threadIdx.x < n)
        dneg[i0 + threadIdx.x] = mins[threadIdx.x][0];
}

// --- 5. positives Gram: 1 wave, 8 i-rows via wave-uniform scalar loads,
//     j-columns per-lane from K-major panel (coalesced b32), zero LDS ---
__global__ __launch_bounds__(64) void k_pos(
    const float* __restrict__ embn, const float* __restrict__ a2,
    const float* __restrict__ panelT, const float* __restrict__ a2p,
    const int* __restrict__ clist, const int* __restrict__ coff,
    const int* __restrict__ ccount, float* __restrict__ candv,
    int* __restrict__ candj, int n) {
    const int c = blockIdx.y;
    const int m = ccount[c];
    const int ig = blockIdx.x >> 1;
    const int jh = blockIdx.x & 1;
    const int i0 = ig * 8;
    if (m == 0 || i0 >= m) return;  // rows don't exist
    const int off = coff[c];
    const int ni = min(8, m - i0);
    const int mh = (m + 1) >> 1;
    const int jbase = jh * mh;
    const int jcount = min(mh, m - jbase);
    const int tid = threadIdx.x;

    // i-row ids: block-uniform indices -> scalar loads / SGPR-held rows
    int gi[8]; float a2i[8];
    const float* arow[8];
#pragma unroll
    for (int r = 0; r < 8; ++r) {
        const int rr = (r < ni) ? r : 0;
        const int g = clist[off + i0 + rr];
        gi[r] = g;
        a2i[r] = a2[g];
        arow[r] = embn + (size_t)g * D;
    }

    // j column 1 (lanes 0..63 consecutive -> coalesced)
    const bool v1 = tid < jcount;
    const int cc1 = v1 ? (off + jbase + tid) : off;
    const int jid1 = v1 ? clist[cc1] : -1;
    const float a2j1 = a2p[cc1];

    float acc1[8];
#pragma unroll
    for (int r = 0; r < 8; ++r) acc1[r] = 0.f;

#pragma unroll 4
    for (int k = 0; k < D; ++k) {
        const float b1 = panelT[(size_t)k * n + cc1];
#pragma unroll
        for (int r = 0; r < 8; ++r) acc1[r] = fmaf(arow[r][k], b1, acc1[r]);
    }

    float rv0[8], rv1[8], rv2[8];
    int rj0[8], rj1[8], rj2[8];
#pragma unroll
    for (int r = 0; r < 8; ++r) {
        rv0[r] = rv1[r] = rv2[r] = -FBIG;
        rj0[r] = rj1[r] = rj2[r] = -1;
        if (r < ni && jid1 >= 0 && jid1 != gi[r]) {
            const float sq = a2i[r] + a2j1 - 2.f * acc1[r];
            ins3(sq, jid1, rv0[r], rv1[r], rv2[r], rj0[r], rj1[r], rj2[r]);
        }
    }

    if (jcount > 64) {  // rare path: class half larger than one wave
        const bool v2 = tid + 64 < jcount;
        const int cc2 = v2 ? (off + jbase + tid + 64) : off;
        const int jid2 = v2 ? clist[cc2] : -1;
        const float a2j2 = a2p[cc2];
        float acc2[8];
#pragma unroll
        for (int r = 0; r < 8; ++r) acc2[r] = 0.f;
#pragma unroll 4
        for (int k = 0; k < D; ++k) {
            const float b2 = panelT[(size_t)k * n + cc2];
#pragma unroll
            for (int r = 0; r < 8; ++r) acc2[r] = fmaf(arow[r][k], b2, acc2[r]);
        }
#pragma unroll
        for (int r = 0; r < 8; ++r) {
            if (r < ni && jid2 >= 0 && jid2 != gi[r]) {
                const float sq = a2i[r] + a2j2 - 2.f * acc2[r];
                ins3(sq, jid2, rv0[r], rv1[r], rv2[r], rj0[r], rj1[r], rj2[r]);
            }
        }
    }

    // 64-lane butterfly merge per i-row (total order -> unique top-3)
#pragma unroll
    for (int o = 32; o > 0; o >>= 1) {
#pragma unroll
        for (int r = 0; r < 8; ++r) {
            const float ov0 = __shfl_xor(rv0[r], o); const int oj0 = __shfl_xor(rj0[r], o);
            const float ov1 = __shfl_xor(rv1[r], o); const int oj1 = __shfl_xor(rj1[r], o);
            const float ov2 = __shfl_xor(rv2[r], o); const int oj2 = __shfl_xor(rj2[r], o);
            ins3(ov0, oj0, rv0[r], rv1[r], rv2[r], rj0[r], rj1[r], rj2[r]);
            ins3(ov1, oj1, rv0[r], rv1[r], rv2[r], rj0[r], rj1[r], rj2[r]);
            ins3(ov2, oj2, rv0[r], rv1[r], rv2[r], rj0[r], rj1[r], rj2[r]);
        }
    }
    if (tid == 0) {
#pragma unroll
        for (int r = 0; r < 8; ++r) {
            if (r < ni) {
                const int base = gi[r] * (NJT * 3) + jh * 3;
                candv[base] = rv0[r]; candv[base + 1] = rv1[r]; candv[base + 2] = rv2[r];
                candj[base] = rj0[r]; candj[base + 1] = rj1[r]; candj[base + 2] = rj2[r];
            }
        }
    }
}

// --- 6. fused: merge candidates -> d_pos -> softplus -> masked-mean reduce ---
// 256 threads = 4 waves, one row per wave. grid = n/4.
__global__ void k_dpos(const float* __restrict__ embn, const float* __restrict__ dneg,
                       const float* __restrict__ candv, const int* __restrict__ candj,
                       float* __restrict__ accum, int* __restrict__ done,
                       float* __restrict__ out, int n, int nblocks) {
    const int tid = threadIdx.x;
    const int wav = tid >> 6, lane = tid & 63;
    const int row = blockIdx.x * 4 + wav;
    float l = 0.f, vv = 0.f;
    float mv0 = -FBIG, mv1 = -FBIG, mv2 = -FBIG;
    int mj0 = -1, mj1 = -1, mj2 = -1;
#pragma unroll
    for (int s = 0; s < NJT * 3; ++s) {
        ins3(candv[row * (NJT * 3) + s], candj[row * (NJT * 3) + s],
             mv0, mv1, mv2, mj0, mj1, mj2);
    }
    const int nw = (mj0 >= 0) + (mj1 >= 0) + (mj2 >= 0);
    if (nw > 0) {
        const int jA = mj0;
        const int jB = (mj1 >= 0) ? mj1 : jA;
        const int jC = (mj2 >= 0) ? mj2 : jB;
        const float4* pi = (const float4*)(embn + (size_t)row * D);
        const float4* r0 = (const float4*)(embn + (size_t)jA * D);
        const float4* r1 = (const float4*)(embn + (size_t)jB * D);
        const float4* r2 = (const float4*)(embn + (size_t)jC * D);
        float accp = 0.f;
#pragma unroll
        for (int s = 0; s < 2; ++s) {
            const int k4 = lane + 64 * s;
            const float4 a = pi[k4];
            const float4 v0 = r0[k4], v1 = r1[k4], v2 = r2[k4];
            const float cx = (v0.x + v1.x + v2.x) * (1.f / 3.f);
            const float cy = (v0.y + v1.y + v2.y) * (1.f / 3.f);
            const float cz = (v0.z + v1.z + v2.z) * (1.f / 3.f);
            const float cw = (v0.w + v1.w + v2.w) * (1.f / 3.f);
            const float dx = a.x - cx, dy = a.y - cy, dz = a.z - cz, dw = a.w - cw;
            accp += dx * dx + dy * dy + dz * dz + dw * dw;
        }
        accp = wave_rsum_all(accp);
        const float dp = sqrtf(fmaxf(accp, FEPS));
        const float x = dp - dneg[row];
        l = fmaxf(x, 0.f) + log1pf(expf(-fabsf(x)));
        vv = 1.f;
    }
    __shared__ float wl[4], wv[4];
    if (lane == 0) { wl[wav] = l; wv[wav] = vv; }
    __syncthreads();
    if (tid == 0) {
        atomicAdd(&accum[0], wl[0] + wl[1] + wl[2] + wl[3]);
        atomicAdd(&accum[1], wv[0] + wv[1] + wv[2] + wv[3]);
        __threadfence();
        const int prev = atomicAdd(done, 1);
        if (prev == nblocks - 1) {
            __threadfence();
            const float sl = atomicAdd(&accum[0], 0.0f);  // coherent-point read
            const float sv = atomicAdd(&accum[1], 0.0f);
            out[0] = sl / fmaxf(sv, 1.0f);
        }
    }
}

extern "C" void kernel_launch(void* const* d_in, const int* in_sizes, int n_in,
                              void* d_out, int out_size, void* d_ws, size_t ws_size,
                              hipStream_t stream) {
    const float* emb = (const float*)d_in[0];
    const int* targets = (const int*)d_in[1];
    const int* ncls = (const int*)d_in[2];
    const int n = in_sizes[1];  // 8192

    float* fp = (float*)d_ws;
    float* embn = fp;    fp += (size_t)n * D;
    float* panelT = fp;  fp += (size_t)n * D;
    float* a2 = fp;      fp += n;
    float* a2p = fp;     fp += n;
    float* centers = fp; fp += (size_t)MAXC * D;
    float* dneg = fp;    fp += n;
    float* candv = fp;   fp += (size_t)n * NJT * 3;
    int* candj = (int*)fp; fp += (size_t)n * NJT * 3;
    int* ccount = (int*)fp; fp += MAXC;
    float* accum = fp;   fp += 2;          // contiguous with ccount: one memset
    int* done = (int*)fp; fp += 1;
    int* coff = (int*)fp;   fp += MAXC;
    int* clist = (int*)fp;  fp += n;

    hipMemsetAsync(ccount, 0, (MAXC + 3) * sizeof(int), stream);

    const int ndp = n / 4;
    k_normalize<<<n, 128, 0, stream>>>(emb, targets, embn, a2, ccount);
    k_build<<<MAXC, 256, 0, stream>>>(targets, ccount, coff, clist, n, ncls);
    k_transpose<<<n / 64, 256, 0, stream>>>(embn, a2, clist, panelT, a2p, n);
    k_centers<<<dim3(4, MAXC), 128, 0, stream>>>(embn, clist, coff, ccount, centers);
    k_dneg<<<(n + DROWS - 1) / DROWS, 128, 0, stream>>>(embn, a2, targets, centers, dneg, n, ncls);
    k_pos<<<dim3(2 * NIG, MAXC), 64, 0, stream>>>(embn, a2, panelT, a2p, clist, coff,
                                                  ccount, candv, candj, n);
    k_dpos<<<ndp, 256, 0, stream>>>(embn, dneg, candv, candj, accum, done, (float*)d_out, n, ndp);
}